// Round 1
// 1081.226 us; speedup vs baseline: 1.4929x; 1.4929x over previous
//
#include <hip/hip_runtime.h>

typedef __attribute__((ext_vector_type(8))) short bf16x8;
typedef __attribute__((ext_vector_type(4))) float f32x4;
typedef __attribute__((ext_vector_type(4))) int i32x4;
typedef __attribute__((ext_vector_type(4))) unsigned short us4;

#define N_HEAD 16
#define SEQ 2048

__device__ __forceinline__ unsigned short f2bf(float f) {
  union { float f; unsigned u; } v; v.f = f;
  unsigned r = v.u + 0x7fffu + ((v.u >> 16) & 1u);
  return (unsigned short)(r >> 16);
}

// ---------------- Kernel 0: f32 -> bf16 pre-convert (x and the 3 weights) ----
// x: 4096x1024 -> xb ; wq/wk/wv: 1024x1024 each -> wb[3]
__global__ void conv_bf16(const float* __restrict__ x,
                          const float* __restrict__ wq,
                          const float* __restrict__ wk,
                          const float* __restrict__ wv,
                          unsigned short* __restrict__ xb,
                          unsigned short* __restrict__ wb)
{
  size_t i = ((size_t)blockIdx.x * 256 + threadIdx.x) * 8;
  const float* src;
  unsigned short* dst;
  size_t off;
  if (i < 4194304) { src = x; dst = xb; off = i; }
  else {
    size_t j = i - 4194304;
    int w = (int)(j >> 20);
    off = j & 1048575u;
    src = (w == 0) ? wq : (w == 1) ? wk : wv;
    dst = wb + ((size_t)w << 20);
  }
  float4 a = *(const float4*)(src + off);
  float4 b = *(const float4*)(src + off + 4);
  us4 u0 = { f2bf(a.x), f2bf(a.y), f2bf(a.z), f2bf(a.w) };
  us4 u1 = { f2bf(b.x), f2bf(b.y), f2bf(b.z), f2bf(b.w) };
  *(us4*)(dst + off) = u0;
  *(us4*)(dst + off + 4) = u1;
}

// ---------------- Kernel 1 (fast): fused QKV projection, bf16 inputs --------
// z=0: q (scaled 0.125) -> [b,h,s,d] bf16
// z=1: k                -> [b,h,s,d] bf16
// z=2: v                -> [b, feature(=h*64+d), s] bf16 (V^T for PV B-operand)
__global__ __launch_bounds__(256, 2)
void qkv_gemm_bf16(const unsigned short* __restrict__ xb,
                   const unsigned short* __restrict__ wb,
                   const float* __restrict__ bq, const float* __restrict__ bk,
                   const float* __restrict__ bv,
                   unsigned short* __restrict__ qws,
                   unsigned short* __restrict__ kws,
                   unsigned short* __restrict__ vtws)
{
  __shared__ unsigned short As[128 * 40];
  __shared__ unsigned short Bs[128 * 40];

  const int tid  = threadIdx.x;
  const int wave = tid >> 6, lane = tid & 63;
  const int quad = lane >> 4, lrow = lane & 15;
  const int wm = wave >> 1, wn = wave & 1;
  const int m0 = blockIdx.x * 128, n0 = blockIdx.y * 128;
  const int z = blockIdx.z;

  const unsigned short* W = wb + ((size_t)z << 20);
  const float* bvec = (z == 0) ? bq : (z == 1) ? bk : bv;

  f32x4 acc[4][4];
  #pragma unroll
  for (int mi = 0; mi < 4; ++mi)
    #pragma unroll
    for (int ni = 0; ni < 4; ++ni)
      acc[mi][ni] = (f32x4){0.f, 0.f, 0.f, 0.f};

  const int srow = tid >> 1, scol = (tid & 1) * 16;
  const unsigned short* xsrc = xb + (size_t)(m0 + srow) * 1024 + scol;
  const unsigned short* wsrc = W  + (size_t)(n0 + srow) * 1024 + scol;

  bf16x8 va0 = *(const bf16x8*)(xsrc);
  bf16x8 va1 = *(const bf16x8*)(xsrc + 8);
  bf16x8 vb0 = *(const bf16x8*)(wsrc);
  bf16x8 vb1 = *(const bf16x8*)(wsrc + 8);

  for (int k0 = 0; k0 < 1024; k0 += 32) {
    __syncthreads();
    *(bf16x8*)&As[srow * 40 + scol]     = va0;
    *(bf16x8*)&As[srow * 40 + scol + 8] = va1;
    *(bf16x8*)&Bs[srow * 40 + scol]     = vb0;
    *(bf16x8*)&Bs[srow * 40 + scol + 8] = vb1;
    __syncthreads();
    if (k0 < 992) {        // prefetch next k-tile while MFMAs run
      va0 = *(const bf16x8*)(xsrc + k0 + 32);
      va1 = *(const bf16x8*)(xsrc + k0 + 40);
      vb0 = *(const bf16x8*)(wsrc + k0 + 32);
      vb1 = *(const bf16x8*)(wsrc + k0 + 40);
    }
    bf16x8 a[4], b[4];
    #pragma unroll
    for (int mi = 0; mi < 4; ++mi)
      a[mi] = *(const bf16x8*)&As[(wm * 64 + mi * 16 + lrow) * 40 + quad * 8];
    #pragma unroll
    for (int ni = 0; ni < 4; ++ni)
      b[ni] = *(const bf16x8*)&Bs[(wn * 64 + ni * 16 + lrow) * 40 + quad * 8];
    #pragma unroll
    for (int mi = 0; mi < 4; ++mi)
      #pragma unroll
      for (int ni = 0; ni < 4; ++ni)
        acc[mi][ni] = __builtin_amdgcn_mfma_f32_16x16x32_bf16(a[mi], b[ni], acc[mi][ni], 0, 0, 0);
  }

  float badd[4];
  #pragma unroll
  for (int ni = 0; ni < 4; ++ni) badd[ni] = bvec[n0 + wn * 64 + ni * 16 + lrow];

  if (z == 2) {
    // V^T: pack 4 token-consecutive values -> one us4 store per (mi,ni)
    #pragma unroll
    for (int mi = 0; mi < 4; ++mi) {
      int i0 = m0 + wm * 64 + mi * 16 + quad * 4;
      int bb = i0 >> 11, ss0 = i0 & 2047;
      #pragma unroll
      for (int ni = 0; ni < 4; ++ni) {
        int j = n0 + wn * 64 + ni * 16 + lrow;     // feature = h*64+d
        us4 u = { f2bf(acc[mi][ni][0] + badd[ni]),
                  f2bf(acc[mi][ni][1] + badd[ni]),
                  f2bf(acc[mi][ni][2] + badd[ni]),
                  f2bf(acc[mi][ni][3] + badd[ni]) };
        *(us4*)(vtws + ((size_t)(bb * 1024 + j)) * 2048 + ss0) = u;
      }
    }
  } else {
    #pragma unroll
    for (int mi = 0; mi < 4; ++mi) {
      #pragma unroll
      for (int ni = 0; ni < 4; ++ni) {
        int j = n0 + wn * 64 + ni * 16 + lrow;
        int hh = j >> 6, dd = j & 63;
        #pragma unroll
        for (int r = 0; r < 4; ++r) {
          int i = m0 + wm * 64 + mi * 16 + quad * 4 + r;
          int bb = i >> 11, ss = i & 2047;
          float y = acc[mi][ni][r] + badd[ni];
          if (z == 0)
            qws[(((size_t)(bb * 16 + hh)) * 2048 + ss) * 64 + dd] = f2bf(y * 0.125f);
          else
            kws[(((size_t)(bb * 16 + hh)) * 2048 + ss) * 64 + dd] = f2bf(y);
        }
      }
    }
  }
}

// ---------------- Kernel 1 (legacy fallback, f32 inputs; unchanged) ---------
__global__ __launch_bounds__(256, 2)
void qkv_gemm(const float* __restrict__ x,
              const float* __restrict__ wq, const float* __restrict__ bq,
              const float* __restrict__ wk, const float* __restrict__ bk,
              const float* __restrict__ wv, const float* __restrict__ bv,
              unsigned short* __restrict__ qws,
              unsigned short* __restrict__ kws,
              unsigned short* __restrict__ vtws)
{
  __shared__ unsigned short As[128 * 40];
  __shared__ unsigned short Bs[128 * 40];

  const int tid  = threadIdx.x;
  const int wave = tid >> 6, lane = tid & 63;
  const int quad = lane >> 4, lrow = lane & 15;
  const int wm = wave >> 1, wn = wave & 1;
  const int m0 = blockIdx.x * 128, n0 = blockIdx.y * 128;
  const int z = blockIdx.z;

  const float* W;  const float* bvec;
  if (z == 0)      { W = wq; bvec = bq; }
  else if (z == 1) { W = wk; bvec = bk; }
  else             { W = wv; bvec = bv; }

  f32x4 acc[4][4];
  #pragma unroll
  for (int mi = 0; mi < 4; ++mi)
    #pragma unroll
    for (int ni = 0; ni < 4; ++ni)
      acc[mi][ni] = (f32x4){0.f, 0.f, 0.f, 0.f};

  for (int k0 = 0; k0 < 1024; k0 += 32) {
    __syncthreads();
    #pragma unroll
    for (int r = 0; r < 4; ++r) {
      int idx = tid + r * 256;
      int row = idx >> 3, seg = idx & 7;
      float4 xa = *(const float4*)(x + (size_t)(m0 + row) * 1024 + k0 + seg * 4);
      float4 xb = *(const float4*)(W + (size_t)(n0 + row) * 1024 + k0 + seg * 4);
      us4 ua = { f2bf(xa.x), f2bf(xa.y), f2bf(xa.z), f2bf(xa.w) };
      us4 ub = { f2bf(xb.x), f2bf(xb.y), f2bf(xb.z), f2bf(xb.w) };
      *(us4*)&As[row * 40 + seg * 4] = ua;
      *(us4*)&Bs[row * 40 + seg * 4] = ub;
    }
    __syncthreads();

    bf16x8 a[4], b[4];
    #pragma unroll
    for (int mi = 0; mi < 4; ++mi)
      a[mi] = *(const bf16x8*)&As[(wm * 64 + mi * 16 + lrow) * 40 + quad * 8];
    #pragma unroll
    for (int ni = 0; ni < 4; ++ni)
      b[ni] = *(const bf16x8*)&Bs[(wn * 64 + ni * 16 + lrow) * 40 + quad * 8];
    #pragma unroll
    for (int mi = 0; mi < 4; ++mi)
      #pragma unroll
      for (int ni = 0; ni < 4; ++ni)
        acc[mi][ni] = __builtin_amdgcn_mfma_f32_16x16x32_bf16(a[mi], b[ni], acc[mi][ni], 0, 0, 0);
  }

  float badd[4];
  #pragma unroll
  for (int ni = 0; ni < 4; ++ni) badd[ni] = bvec[n0 + wn * 64 + ni * 16 + lrow];

  #pragma unroll
  for (int mi = 0; mi < 4; ++mi) {
    #pragma unroll
    for (int ni = 0; ni < 4; ++ni) {
      int j = n0 + wn * 64 + ni * 16 + lrow;
      int hh = j >> 6, dd = j & 63;
      #pragma unroll
      for (int r = 0; r < 4; ++r) {
        int i = m0 + wm * 64 + mi * 16 + quad * 4 + r;
        int bb = i >> 11, ss = i & 2047;
        float y = acc[mi][ni][r] + badd[ni];
        if (z == 0)
          qws[(((size_t)(bb * 16 + hh)) * 2048 + ss) * 64 + dd] = f2bf(y * 0.125f);
        else if (z == 1)
          kws[(((size_t)(bb * 16 + hh)) * 2048 + ss) * 64 + dd] = f2bf(y);
        else
          vtws[(((size_t)(bb * 16 + hh)) * 64 + dd) * 2048 + ss] = f2bf(y);
      }
    }
  }
}

// ---------------- Kernel 2: fused attention, swapped-operand layout ---------
// Block = (bh-pair, 16-q-row strip), 512 threads = 8 waves; wave owns 256 cols.
// QK^T computed as mfma(K, Q) so each lane holds 4 CONSECUTIVE k-cols of its
// own q-row (q-row = lane&15): bias/mask -> float4/int4 loads, weights ->
// float4 stores, row-sum -> per-lane + 2 shfl. No max pass (|logits| << 80).
__global__ __launch_bounds__(512, 4)
void attn2(const unsigned short* __restrict__ qws,
           const unsigned short* __restrict__ kws,
           const unsigned short* __restrict__ vtws,
           const float* __restrict__ bias,
           const int* __restrict__ mask,
           float* __restrict__ out)
{
  const int tid  = threadIdx.x;
  const int wave = tid >> 6, lane = tid & 63;
  const int quad = lane >> 4, lrow = lane & 15;
  const int bx = blockIdx.x;                 // 0..31, bh-pairs adjacent
  const int h = bx >> 1, bb = bx & 1, bh = bb * 16 + h;
  const int q0 = blockIdx.y * 16;
  const int cb = wave * 256;

  const unsigned short* qh  = qws  + (size_t)bh * SEQ * 64;
  const unsigned short* kh  = kws  + (size_t)bh * SEQ * 64;
  const unsigned short* vth = vtws + (size_t)bh * 64 * SEQ;
  float* out_o = out;
  float* out_w = out + (size_t)2 * N_HEAD * SEQ * 64;

  __shared__ float red[8][16];
  __shared__ unsigned short pbuf[8][16][40];   // per-wave P bounce, b128-aligned rows
  __shared__ float obuf[8][16][68];            // cross-wave PV reduce (+4 pad)

  // Q fragment (B-operand of swapped QK^T): lane -> Q[q=lrow][k=quad*8+j]
  bf16x8 aq[2];
  #pragma unroll
  for (int ks = 0; ks < 2; ++ks)
    aq[ks] = *(const bf16x8*)(qh + (size_t)(q0 + lrow) * 64 + ks * 32 + quad * 8);

  const unsigned short* kp = kh + (size_t)(cb + lrow) * 64 + quad * 8;
  const float* bp = bias + ((size_t)h * SEQ + q0 + lrow) * SEQ + cb + quad * 4;
  const int*   mp = mask + (size_t)(q0 + lrow) * SEQ + cb + quad * 4;

  const float L2E = 1.44269504f;
  f32x4 S[16];          // e-values: lane&15 = q-row, cols = cb + t*16 + quad*4 + r
  float rsum = 0.f;

  #pragma unroll
  for (int t = 0; t < 16; ++t) {
    bf16x8 k0f = *(const bf16x8*)(kp + t * 1024);        // k-rows c0..c0+15, d 0..31
    bf16x8 k1f = *(const bf16x8*)(kp + t * 1024 + 32);   // d 32..63
    f32x4 c = (f32x4){0.f, 0.f, 0.f, 0.f};
    c = __builtin_amdgcn_mfma_f32_16x16x32_bf16(k0f, aq[0], c, 0, 0, 0);
    c = __builtin_amdgcn_mfma_f32_16x16x32_bf16(k1f, aq[1], c, 0, 0, 0);
    f32x4 bbv = *(const f32x4*)(bp + t * 16);
    i32x4 mmv = *(const i32x4*)(mp + t * 16);
    #pragma unroll
    for (int r = 0; r < 4; ++r) {
      float e = (mmv[r] == 0) ? 0.f : exp2f((c[r] + bbv[r]) * L2E);
      S[t][r] = e;
      rsum += e;
    }
  }

  // row sum: quads of same q-row, then cross-wave via LDS
  rsum += __shfl_xor(rsum, 16);
  rsum += __shfl_xor(rsum, 32);
  if (lane < 16) red[wave][lrow] = rsum;
  __syncthreads();
  float tot = 0.f;
  #pragma unroll
  for (int w = 0; w < 8; ++w) tot += red[w][lrow];
  const float inv = 1.0f / tot;

  f32x4 O[4];
  #pragma unroll
  for (int n = 0; n < 4; ++n) O[n] = (f32x4){0.f, 0.f, 0.f, 0.f};

  float* wbase = out_w + ((size_t)bh * SEQ + q0 + lrow) * SEQ + cb + quad * 4;
  const unsigned short* vp = vth + (size_t)lrow * SEQ + cb + quad * 8;

  // normalize + write weights (float4) + PV per 32-col window
  #pragma unroll
  for (int cc = 0; cc < 8; ++cc) {
    #pragma unroll
    for (int tt = 0; tt < 2; ++tt) {
      const int t = cc * 2 + tt;
      f32x4 wv;
      #pragma unroll
      for (int r = 0; r < 4; ++r) wv[r] = S[t][r] * inv;
      *(f32x4*)(wbase + t * 16) = wv;
      us4 u = { f2bf(wv[0]), f2bf(wv[1]), f2bf(wv[2]), f2bf(wv[3]) };
      *(us4*)&pbuf[wave][lrow][tt * 16 + quad * 4] = u;
    }
    asm volatile("s_waitcnt lgkmcnt(0)" ::: "memory");  // wave-internal LDS RAW
    bf16x8 aw = *(const bf16x8*)&pbuf[wave][lrow][quad * 8];
    #pragma unroll
    for (int n = 0; n < 4; ++n) {
      bf16x8 v8 = *(const bf16x8*)(vp + (size_t)n * 16 * SEQ + cc * 32);
      O[n] = __builtin_amdgcn_mfma_f32_16x16x32_bf16(aw, v8, O[n], 0, 0, 0);
    }
  }

  // cross-wave reduce of O, write first output
  #pragma unroll
  for (int n = 0; n < 4; ++n)
    #pragma unroll
    for (int r = 0; r < 4; ++r)
      obuf[wave][quad * 4 + r][n * 16 + lrow] = O[n][r];
  __syncthreads();
  #pragma unroll
  for (int e = 0; e < 2; ++e) {
    int idx = e * 512 + tid;
    int row = idx >> 6, dd = idx & 63;
    float v = 0.f;
    #pragma unroll
    for (int w = 0; w < 8; ++w) v += obuf[w][row][dd];
    out_o[((size_t)bh * SEQ + q0 + row) * 64 + dd] = v;
  }
}

extern "C" void kernel_launch(void* const* d_in, const int* in_sizes, int n_in,
                              void* d_out, int out_size, void* d_ws, size_t ws_size,
                              hipStream_t stream) {
  const float* x    = (const float*)d_in[0];
  const float* bias = (const float*)d_in[1];
  const int*   mask = (const int*)d_in[2];
  const float* wq   = (const float*)d_in[3];
  const float* bq   = (const float*)d_in[4];
  const float* wk   = (const float*)d_in[5];
  const float* bk   = (const float*)d_in[6];
  const float* wv   = (const float*)d_in[7];
  const float* bv   = (const float*)d_in[8];

  unsigned short* qws  = (unsigned short*)d_ws;           // 8 MB
  unsigned short* kws  = qws + (size_t)4194304;           // 8 MB
  unsigned short* vtws = kws + (size_t)4194304;           // 8 MB (V^T)
  float* out = (float*)d_out;

  if (ws_size >= (size_t)39845888) {
    unsigned short* xb = vtws + (size_t)4194304;          // 8 MB bf16 x
    unsigned short* wb = xb + (size_t)4194304;            // 6 MB bf16 wq|wk|wv
    conv_bf16<<<dim3(3584), 256, 0, stream>>>(x, wq, wk, wv, xb, wb);
    qkv_gemm_bf16<<<dim3(32, 8, 3), 256, 0, stream>>>(xb, wb, bq, bk, bv,
                                                      qws, kws, vtws);
  } else {
    qkv_gemm<<<dim3(32, 8, 3), 256, 0, stream>>>(x, wq, bq, wk, bk, wv, bv,
                                                 qws, kws, vtws);
  }
  // grid: x = bh-pairs (b=0/1 sharing bias rows are adjacent), y = q-strips
  attn2<<<dim3(32, 128), 512, 0, stream>>>(qws, kws, vtws, bias, mask, out);
}